// Round 2
// baseline (1641.633 us; speedup 1.0000x reference)
//
#include <hip/hip_runtime.h>
#include <hip/hip_bf16.h>

namespace {

constexpr int B = 2;
constexpr int N = 40000;
constexpr int E = 400000;
constexpr int R = 64;
constexpr int D = 64;
constexpr int L = 6;
constexpr float EPS = 1e-5f;

// ---- query gather + boundary scatter (x must be pre-zeroed) ----
__global__ void k_init(const float* __restrict__ rel_reps,
                       const int* __restrict__ h_index, const int* __restrict__ r_index,
                       float* __restrict__ x, float* __restrict__ query) {
  int t = threadIdx.x;           // 128 threads
  int b = t >> 6, d = t & 63;
  float q = rel_reps[(b * R + r_index[b]) * D + d];
  query[b * D + d] = q;
  x[((size_t)b * N + h_index[b]) * D + d] = q;
}

// ---- relation projection MLP for all layers: rel_all[l,b,r,d] ----
__global__ __launch_bounds__(64) void k_rel(
    const float* __restrict__ rel_reps,
    const float* __restrict__ pw1, const float* __restrict__ pb1,
    const float* __restrict__ pw2, const float* __restrict__ pb2,
    float* __restrict__ rel_all) {
  __shared__ float row[D];
  __shared__ float row2[D];
  int idx = blockIdx.x;             // [0, L*B*R)
  int l = idx / (B * R);
  int br = idx - l * (B * R);       // = b*R + r
  int d = threadIdx.x;
  row[d] = rel_reps[(size_t)br * D + d];
  __syncthreads();
  const float* w1 = pw1 + (size_t)l * D * D;
  float acc = pb1[l * D + d];
  for (int k = 0; k < D; ++k) acc = fmaf(row[k], w1[k * D + d], acc);
  row2[d] = fmaxf(acc, 0.f);
  __syncthreads();
  const float* w2 = pw2 + (size_t)l * D * D;
  float acc2 = pb2[l * D + d];
  for (int k = 0; k < D; ++k) acc2 = fmaf(row2[k], w2[k * D + d], acc2);
  rel_all[(size_t)idx * D + d] = acc2;
}

// ---- edge message + scatter-add: one wave per edge, both batches ----
__global__ __launch_bounds__(256) void k_scatter(
    const float* __restrict__ x, const float* __restrict__ rel,  // rel: [B,R,D] this layer
    const int* __restrict__ src, const int* __restrict__ dst,
    const int* __restrict__ etype, const int* __restrict__ h_index,
    float* __restrict__ agg, int first) {
  int lane = threadIdx.x & 63;
  int warp = (blockIdx.x * blockDim.x + threadIdx.x) >> 6;
  int nwarps = (gridDim.x * blockDim.x) >> 6;
  int h0 = h_index[0], h1 = h_index[1];
  for (int e = warp; e < E; e += nwarps) {
    int s = src[e];
    if (first && s != h0 && s != h1) continue;  // layer 0: x is boundary-sparse
    int t = etype[e];
    int dn = dst[e];
    if (!first || s == h0) {
      float v = x[(size_t)s * D + lane] * rel[(size_t)t * D + lane];
      atomicAdd(&agg[(size_t)dn * D + lane], v);
    }
    if (!first || s == h1) {
      float v = x[((size_t)N + s) * D + lane] * rel[((size_t)R + t) * D + lane];
      atomicAdd(&agg[((size_t)N + dn) * D + lane], v);
    }
  }
}

// ---- node update: concat(x, agg+boundary) @ lin_w + lin_b, LN, relu, +x (in place) ----
__global__ __launch_bounds__(256) void k_node(
    float* __restrict__ x, const float* __restrict__ agg,
    const float* __restrict__ query, const int* __restrict__ h_index,
    const float* __restrict__ lin_w, const float* __restrict__ lin_b,
    const float* __restrict__ ln_g, const float* __restrict__ ln_b,
    int layer) {
  __shared__ float w[2 * D][D];       // 32 KB fp32 weights, [k][d]
  __shared__ float bias_s[D], g_s[D], b_s[D];
  __shared__ float rows[4][2 * D];    // per-wave input row
  int tid = threadIdx.x;
  const float* lw = lin_w + (size_t)layer * 2 * D * D;
  for (int i = tid; i < 2 * D * D; i += 256) (&w[0][0])[i] = lw[i];
  if (tid < D) {
    bias_s[tid] = lin_b[layer * D + tid];
    g_s[tid]    = ln_g[layer * D + tid];
    b_s[tid]    = ln_b[layer * D + tid];
  }
  __syncthreads();
  int wid = tid >> 6, lane = tid & 63;
  int node = blockIdx.x * 4 + wid;    // B*N = 80000 = 20000 blocks * 4, no remainder
  int b = node / N;
  int n = node - b * N;
  size_t off = (size_t)node * D;
  float xv = x[off + lane];
  float av = agg[off + lane];
  if (n == h_index[b]) av += query[b * D + lane];  // + boundary
  rows[wid][lane] = xv;
  rows[wid][D + lane] = av;
  __syncthreads();
  float acc = bias_s[lane];
  #pragma unroll 16
  for (int k = 0; k < 2 * D; ++k) acc = fmaf(rows[wid][k], w[k][lane], acc);
  // LayerNorm across the 64 outputs (one per lane) via wave shuffles
  float s1 = acc, s2 = acc * acc;
  #pragma unroll
  for (int m = 32; m > 0; m >>= 1) {
    s1 += __shfl_xor(s1, m);
    s2 += __shfl_xor(s2, m);
  }
  float mu = s1 * (1.f / D);
  float var = s2 * (1.f / D) - mu * mu;
  float o = (acc - mu) * rsqrtf(var + EPS) * g_s[lane] + b_s[lane];
  o = fmaxf(o, 0.f) + xv;            // relu + short-cut
  x[off + lane] = o;                 // in-place: row (b,n) touched only by this wave
}

// ---- final MLP: relu(concat(x, query) @ mlp_w + mlp_b) -> fp32 out ----
// Weights staged in LDS as packed bf16 pairs (32 KB) to fit beside row buffer;
// 2% test threshold dwarfs the ~0.4% bf16 quantization.
__global__ __launch_bounds__(256) void k_mlp(
    const float* __restrict__ x, const float* __restrict__ query,
    const float* __restrict__ mlp_w,            // [2D][2D] row-major fp32
    const float* __restrict__ mlp_b,
    float2* __restrict__ out) {
  __shared__ unsigned int w[2 * D][D];   // [k][j-pair], packed bf16, 32 KB
  __shared__ float rows[4][2 * D];
  int tid = threadIdx.x;
  for (int i = tid; i < D * D; i += 256) {   // D*D pairs = 4096 words... 2D*2D/2 = 8192
  }
  for (int i = tid; i < 2 * D * D; i += 256) {
    // pack columns (2j, 2j+1) of row k: element index = 2*i, 2*i+1 of flat array
    float lo = mlp_w[2 * i];
    float hi = mlp_w[2 * i + 1];
    unsigned int ulo = (__float_as_uint(lo) + 0x8000u) >> 16;        // rne-ish bf16
    unsigned int uhi = (__float_as_uint(hi) + 0x8000u) & 0xffff0000u;
    (&w[0][0])[i] = (ulo & 0xffffu) | uhi;
  }
  __syncthreads();
  int wid = tid >> 6, lane = tid & 63;
  int node = blockIdx.x * 4 + wid;
  int b = node / N;
  size_t off = (size_t)node * D;
  rows[wid][lane] = x[off + lane];
  rows[wid][D + lane] = query[b * D + lane];
  __syncthreads();
  float acc0 = mlp_b[2 * lane];
  float acc1 = mlp_b[2 * lane + 1];
  #pragma unroll 16
  for (int k = 0; k < 2 * D; ++k) {
    float a = rows[wid][k];
    unsigned int pw = w[k][lane];
    float lo = __uint_as_float(pw << 16);
    float hi = __uint_as_float(pw & 0xffff0000u);
    acc0 = fmaf(a, lo, acc0);
    acc1 = fmaf(a, hi, acc1);
  }
  float2 o;
  o.x = fmaxf(acc0, 0.f);
  o.y = fmaxf(acc1, 0.f);
  out[off + lane] = o;   // pair index: node*64 + lane -> elements node*128+2lane,+1
}

}  // namespace

extern "C" void kernel_launch(void* const* d_in, const int* in_sizes, int n_in,
                              void* d_out, int out_size, void* d_ws, size_t ws_size,
                              hipStream_t stream) {
  const float* rel_reps = (const float*)d_in[0];
  const int* h_index    = (const int*)d_in[1];
  const int* r_index    = (const int*)d_in[2];
  const int* edge_index = (const int*)d_in[3];
  const int* edge_type  = (const int*)d_in[4];
  const float* proj_w1  = (const float*)d_in[5];
  const float* proj_b1  = (const float*)d_in[6];
  const float* proj_w2  = (const float*)d_in[7];
  const float* proj_b2  = (const float*)d_in[8];
  const float* lin_w    = (const float*)d_in[9];
  const float* lin_b    = (const float*)d_in[10];
  const float* ln_g     = (const float*)d_in[11];
  const float* ln_b     = (const float*)d_in[12];
  const float* mlp_w    = (const float*)d_in[13];
  const float* mlp_b    = (const float*)d_in[14];

  // workspace layout (fp32): x | agg | rel_all | query  (~41.2 MB)
  float* x       = (float*)d_ws;
  float* agg     = x + (size_t)B * N * D;
  float* rel_all = agg + (size_t)B * N * D;
  float* query   = rel_all + (size_t)L * B * R * D;

  const int* srcp = edge_index;
  const int* dstp = edge_index + E;

  hipMemsetAsync(x, 0, (size_t)B * N * D * sizeof(float), stream);
  k_init<<<1, 128, 0, stream>>>(rel_reps, h_index, r_index, x, query);
  k_rel<<<L * B * R, 64, 0, stream>>>(rel_reps, proj_w1, proj_b1, proj_w2, proj_b2, rel_all);

  for (int l = 0; l < L; ++l) {
    hipMemsetAsync(agg, 0, (size_t)B * N * D * sizeof(float), stream);
    k_scatter<<<4096, 256, 0, stream>>>(x, rel_all + (size_t)l * B * R * D,
                                        srcp, dstp, edge_type, h_index, agg,
                                        (l == 0) ? 1 : 0);
    k_node<<<(B * N) / 4, 256, 0, stream>>>(x, agg, query, h_index,
                                            lin_w, lin_b, ln_g, ln_b, l);
  }
  k_mlp<<<(B * N) / 4, 256, 0, stream>>>(x, query, mlp_w, mlp_b,
                                         (float2*)d_out);
}

// Round 3
// 1197.014 us; speedup vs baseline: 1.3714x; 1.3714x over previous
//
#include <hip/hip_runtime.h>
#include <hip/hip_bf16.h>

namespace {

constexpr int B = 2;
constexpr int N = 40000;
constexpr int E = 400000;
constexpr int R = 64;
constexpr int D = 64;
constexpr int L = 6;
constexpr float EPS = 1e-5f;

// ---- query gather + boundary scatter (x0 must be pre-zeroed) ----
__global__ void k_init(const float* __restrict__ rel_reps,
                       const int* __restrict__ h_index, const int* __restrict__ r_index,
                       float* __restrict__ x, float* __restrict__ query) {
  int t = threadIdx.x;           // 128 threads
  int b = t >> 6, d = t & 63;
  float q = rel_reps[(b * R + r_index[b]) * D + d];
  query[b * D + d] = q;
  x[((size_t)b * N + h_index[b]) * D + d] = q;
}

// ---- relation projection MLP for all layers: rel_all[l,b,r,d] ----
__global__ __launch_bounds__(64) void k_rel(
    const float* __restrict__ rel_reps,
    const float* __restrict__ pw1, const float* __restrict__ pb1,
    const float* __restrict__ pw2, const float* __restrict__ pb2,
    float* __restrict__ rel_all) {
  __shared__ float row[D];
  __shared__ float row2[D];
  int idx = blockIdx.x;             // [0, L*B*R)
  int l = idx / (B * R);
  int br = idx - l * (B * R);
  int d = threadIdx.x;
  row[d] = rel_reps[(size_t)br * D + d];
  __syncthreads();
  const float* w1 = pw1 + (size_t)l * D * D;
  float acc = pb1[l * D + d];
  for (int k = 0; k < D; ++k) acc = fmaf(row[k], w1[k * D + d], acc);
  row2[d] = fmaxf(acc, 0.f);
  __syncthreads();
  const float* w2 = pw2 + (size_t)l * D * D;
  float acc2 = pb2[l * D + d];
  for (int k = 0; k < D; ++k) acc2 = fmaf(row2[k], w2[k * D + d], acc2);
  rel_all[(size_t)idx * D + d] = acc2;
}

// ---- CSR build: histogram of dst ----
__global__ __launch_bounds__(256) void k_hist(const int* __restrict__ dst,
                                              int* __restrict__ cnt) {
  int e = blockIdx.x * 256 + threadIdx.x;
  if (e < E) atomicAdd(&cnt[dst[e]], 1);
}

// ---- CSR build: single-block exclusive scan over cnt[N] -> row_ptr, cursor ----
__global__ __launch_bounds__(256) void k_scan(const int* __restrict__ cnt,
                                              int* __restrict__ row_ptr,
                                              int* __restrict__ cursor) {
  __shared__ int part[257];
  int t = threadIdx.x;
  const int CH = (N + 255) / 256;   // 157
  int lo = t * CH, hi = min(lo + CH, N);
  int s = 0;
  for (int i = lo; i < hi; ++i) s += cnt[i];
  part[t + 1] = s;
  __syncthreads();
  if (t == 0) {
    part[0] = 0;
    for (int i = 1; i <= 256; ++i) part[i] += part[i - 1];
  }
  __syncthreads();
  int run = part[t];
  for (int i = lo; i < hi; ++i) {
    row_ptr[i] = run;
    cursor[i]  = run;
    run += cnt[i];
  }
  if (t == 255) row_ptr[N] = part[256];
}

// ---- CSR build: fill edge slots with packed src | etype<<16 ----
__global__ __launch_bounds__(256) void k_fill(const int* __restrict__ src,
                                              const int* __restrict__ dst,
                                              const int* __restrict__ etype,
                                              int* __restrict__ cursor,
                                              unsigned int* __restrict__ es) {
  int e = blockIdx.x * 256 + threadIdx.x;
  if (e < E) {
    int p = atomicAdd(&cursor[dst[e]], 1);
    es[p] = (unsigned int)src[e] | ((unsigned int)etype[e] << 16);  // src < 65536
  }
}

// ---- fused layer: CSR segmented-sum + boundary + linear + LN + relu + shortcut ----
// block = 256 (4 waves), each wave handles 8 nodes (both batches) -> 32 nodes/block
__global__ __launch_bounds__(256) void k_layer(
    const float* __restrict__ xo, float* __restrict__ xn,
    const float* __restrict__ rel,              // [B,R,D] this layer (64 KB, L1/L2 hot)
    const int* __restrict__ row_ptr, const unsigned int* __restrict__ es,
    const float* __restrict__ query, const int* __restrict__ h_index,
    const float* __restrict__ lin_w, const float* __restrict__ lin_b,
    const float* __restrict__ ln_g, const float* __restrict__ ln_b,
    int layer, int first) {
  __shared__ float w[2 * D][D];        // 32 KB, [k][out]; 2-way bank alias = free
  __shared__ float bias_s[D], g_s[D], b_s[D];
  __shared__ float rows[4][2][2 * D];  // per-wave input rows, both batches
  int tid = threadIdx.x;
  const float* lw = lin_w + (size_t)layer * 2 * D * D;
  for (int i = tid; i < 2 * D * D; i += 256) (&w[0][0])[i] = lw[i];
  if (tid < D) {
    bias_s[tid] = lin_b[layer * D + tid];
    g_s[tid]    = ln_g[layer * D + tid];
    b_s[tid]    = ln_b[layer * D + tid];
  }
  int h0 = h_index[0], h1 = h_index[1];
  __syncthreads();
  int wid = tid >> 6, lane = tid & 63;
  int base = blockIdx.x * 32 + wid * 8;   // N = 40000 = 1250 blocks * 32
  for (int ni = 0; ni < 8; ++ni) {
    int n = base + ni;
    float a0 = 0.f, a1 = 0.f;
    int rs = row_ptr[n], re = row_ptr[n + 1];
    if (first) {
      // layer 0: x is nonzero only at h0 (b=0) and h1 (b=1)
      for (int j = rs; j < re; ++j) {
        unsigned int pk = es[j];
        int s  = (int)(pk & 0xffffu);
        int et = (int)(pk >> 16);
        if (s == h0) a0 = fmaf(xo[(size_t)s * D + lane], rel[et * D + lane], a0);
        if (s == h1) a1 = fmaf(xo[((size_t)N + s) * D + lane], rel[(R + et) * D + lane], a1);
      }
    } else {
      for (int j = rs; j < re; ++j) {
        unsigned int pk = es[j];
        int s  = (int)(pk & 0xffffu);
        int et = (int)(pk >> 16);
        a0 = fmaf(xo[(size_t)s * D + lane], rel[et * D + lane], a0);
        a1 = fmaf(xo[((size_t)N + s) * D + lane], rel[(R + et) * D + lane], a1);
      }
    }
    if (n == h0) a0 += query[lane];        // + boundary
    if (n == h1) a1 += query[D + lane];
    float xv0 = xo[(size_t)n * D + lane];
    float xv1 = xo[((size_t)N + n) * D + lane];
    rows[wid][0][lane] = xv0; rows[wid][0][D + lane] = a0;
    rows[wid][1][lane] = xv1; rows[wid][1][D + lane] = a1;
    __syncthreads();   // uniform trip count across all 4 waves; orders LDS rows
    float o0 = bias_s[lane], o1 = o0;
    #pragma unroll 8
    for (int k = 0; k < 2 * D; ++k) {
      float wk = w[k][lane];
      o0 = fmaf(rows[wid][0][k], wk, o0);
      o1 = fmaf(rows[wid][1][k], wk, o1);
    }
    // LayerNorm across 64 outputs (one per lane), both batches
    float s10 = o0, s20 = o0 * o0, s11 = o1, s21 = o1 * o1;
    #pragma unroll
    for (int m = 32; m > 0; m >>= 1) {
      s10 += __shfl_xor(s10, m); s20 += __shfl_xor(s20, m);
      s11 += __shfl_xor(s11, m); s21 += __shfl_xor(s21, m);
    }
    float mu0 = s10 * (1.f / D), var0 = s20 * (1.f / D) - mu0 * mu0;
    float mu1 = s11 * (1.f / D), var1 = s21 * (1.f / D) - mu1 * mu1;
    float r0 = fmaxf((o0 - mu0) * rsqrtf(var0 + EPS) * g_s[lane] + b_s[lane], 0.f) + xv0;
    float r1 = fmaxf((o1 - mu1) * rsqrtf(var1 + EPS) * g_s[lane] + b_s[lane], 0.f) + xv1;
    xn[(size_t)n * D + lane] = r0;
    xn[((size_t)N + n) * D + lane] = r1;
  }
}

// ---- final MLP: relu(concat(x, query) @ mlp_w + mlp_b) -> fp32 out ----
// block = 256 (4 waves), each wave 16 nodes (both batches) -> 64 nodes/block
__global__ __launch_bounds__(256) void k_mlp(
    const float* __restrict__ x, const float* __restrict__ query,
    const float* __restrict__ mlp_w,            // [2D][2D] row-major fp32
    const float* __restrict__ mlp_b,
    float2* __restrict__ out) {
  __shared__ unsigned int w[2 * D][D];   // packed bf16 col-pairs, 32 KB
  __shared__ float rows[4][2][2 * D];
  int tid = threadIdx.x;
  for (int i = tid; i < 2 * D * D; i += 256) {
    float lo = mlp_w[2 * i];
    float hi = mlp_w[2 * i + 1];
    unsigned int ulo = (__float_as_uint(lo) + 0x8000u) >> 16;
    unsigned int uhi = (__float_as_uint(hi) + 0x8000u) & 0xffff0000u;
    (&w[0][0])[i] = (ulo & 0xffffu) | uhi;
  }
  int wid = tid >> 6, lane = tid & 63;
  // query half of each row is node-invariant: write once
  rows[wid][0][D + lane] = query[lane];
  rows[wid][1][D + lane] = query[D + lane];
  __syncthreads();
  float b0 = mlp_b[2 * lane], b1 = mlp_b[2 * lane + 1];
  int base = blockIdx.x * 64 + wid * 16;   // N = 40000 = 625 blocks * 64
  for (int ni = 0; ni < 16; ++ni) {
    int n = base + ni;
    rows[wid][0][lane] = x[(size_t)n * D + lane];
    rows[wid][1][lane] = x[((size_t)N + n) * D + lane];
    __syncthreads();   // uniform; orders LDS rows
    float a00 = b0, a01 = b1, a10 = b0, a11 = b1;
    #pragma unroll 8
    for (int k = 0; k < 2 * D; ++k) {
      unsigned int pw = w[k][lane];
      float wlo = __uint_as_float(pw << 16);
      float whi = __uint_as_float(pw & 0xffff0000u);
      float r0 = rows[wid][0][k], r1 = rows[wid][1][k];
      a00 = fmaf(r0, wlo, a00); a01 = fmaf(r0, whi, a01);
      a10 = fmaf(r1, wlo, a10); a11 = fmaf(r1, whi, a11);
    }
    float2 o0, o1;
    o0.x = fmaxf(a00, 0.f); o0.y = fmaxf(a01, 0.f);
    o1.x = fmaxf(a10, 0.f); o1.y = fmaxf(a11, 0.f);
    out[(size_t)n * D + lane] = o0;            // elements node*128 + 2lane(+1)
    out[((size_t)N + n) * D + lane] = o1;
  }
}

}  // namespace

extern "C" void kernel_launch(void* const* d_in, const int* in_sizes, int n_in,
                              void* d_out, int out_size, void* d_ws, size_t ws_size,
                              hipStream_t stream) {
  const float* rel_reps = (const float*)d_in[0];
  const int* h_index    = (const int*)d_in[1];
  const int* r_index    = (const int*)d_in[2];
  const int* edge_index = (const int*)d_in[3];
  const int* edge_type  = (const int*)d_in[4];
  const float* proj_w1  = (const float*)d_in[5];
  const float* proj_b1  = (const float*)d_in[6];
  const float* proj_w2  = (const float*)d_in[7];
  const float* proj_b2  = (const float*)d_in[8];
  const float* lin_w    = (const float*)d_in[9];
  const float* lin_b    = (const float*)d_in[10];
  const float* ln_g     = (const float*)d_in[11];
  const float* ln_b     = (const float*)d_in[12];
  const float* mlp_w    = (const float*)d_in[13];
  const float* mlp_b    = (const float*)d_in[14];

  // workspace layout: x0 | x1 | rel_all | query | cnt | row_ptr | cursor | es
  float* x0      = (float*)d_ws;
  float* x1      = x0 + (size_t)B * N * D;
  float* rel_all = x1 + (size_t)B * N * D;
  float* query   = rel_all + (size_t)L * B * R * D;
  int*   cnt     = (int*)(query + B * D);
  int*   row_ptr = cnt + N;
  int*   cursor  = row_ptr + (N + 1);
  unsigned int* es = (unsigned int*)(cursor + N);

  const int* srcp = edge_index;
  const int* dstp = edge_index + E;

  hipMemsetAsync(x0, 0, (size_t)B * N * D * sizeof(float), stream);
  hipMemsetAsync(cnt, 0, N * sizeof(int), stream);
  k_init<<<1, 128, 0, stream>>>(rel_reps, h_index, r_index, x0, query);
  k_rel<<<L * B * R, 64, 0, stream>>>(rel_reps, proj_w1, proj_b1, proj_w2, proj_b2, rel_all);
  k_hist<<<(E + 255) / 256, 256, 0, stream>>>(dstp, cnt);
  k_scan<<<1, 256, 0, stream>>>(cnt, row_ptr, cursor);
  k_fill<<<(E + 255) / 256, 256, 0, stream>>>(srcp, dstp, edge_type, cursor, es);

  float* xo = x0;
  float* xn = x1;
  for (int l = 0; l < L; ++l) {
    k_layer<<<N / 32, 256, 0, stream>>>(xo, xn, rel_all + (size_t)l * B * R * D,
                                        row_ptr, es, query, h_index,
                                        lin_w, lin_b, ln_g, ln_b, l, (l == 0) ? 1 : 0);
    float* t = xo; xo = xn; xn = t;
  }
  // after 6 layers result is back in x0 (xo)
  k_mlp<<<N / 64, 256, 0, stream>>>(xo, query, mlp_w, mlp_b, (float2*)d_out);
}

// Round 4
// 752.439 us; speedup vs baseline: 2.1818x; 1.5908x over previous
//
#include <hip/hip_runtime.h>
#include <hip/hip_bf16.h>

namespace {

constexpr int B = 2;
constexpr int N = 40000;
constexpr int E = 400000;
constexpr int R = 64;
constexpr int D = 64;
constexpr int L = 6;
constexpr float EPS = 1e-5f;

// Batch-interleaved layout everywhere: float2 element = (batch0, batch1).

// ---- query gather + boundary scatter (x must be pre-zeroed) ----
__global__ void k_init(const float* __restrict__ rel_reps,
                       const int* __restrict__ h_index, const int* __restrict__ r_index,
                       float* __restrict__ x_f, float* __restrict__ query_f) {
  int t = threadIdx.x;           // 128 threads
  int b = t >> 6, d = t & 63;
  float q = rel_reps[(b * R + r_index[b]) * D + d];
  query_f[d * 2 + b] = q;
  x_f[((size_t)h_index[b] * D + d) * 2 + b] = q;
}

// ---- relation projection MLP for all layers: rel2[l][r*64+d] = (b0, b1) ----
__global__ __launch_bounds__(64) void k_rel(
    const float* __restrict__ rel_reps,
    const float* __restrict__ pw1, const float* __restrict__ pb1,
    const float* __restrict__ pw2, const float* __restrict__ pb2,
    float* __restrict__ rel_f) {
  __shared__ float row[D];
  __shared__ float row2[D];
  int idx = blockIdx.x;             // [0, L*B*R)
  int l = idx / (B * R);
  int br = idx - l * (B * R);       // b*R + r
  int b = br / R, r = br - b * R;
  int d = threadIdx.x;
  row[d] = rel_reps[(size_t)br * D + d];
  __syncthreads();
  const float* w1 = pw1 + (size_t)l * D * D;
  float acc = pb1[l * D + d];
  for (int k = 0; k < D; ++k) acc = fmaf(row[k], w1[k * D + d], acc);
  row2[d] = fmaxf(acc, 0.f);
  __syncthreads();
  const float* w2 = pw2 + (size_t)l * D * D;
  float acc2 = pb2[l * D + d];
  for (int k = 0; k < D; ++k) acc2 = fmaf(row2[k], w2[k * D + d], acc2);
  rel_f[(((size_t)l * R + r) * D + d) * 2 + b] = acc2;
}

// ---- CSR build ----
__global__ __launch_bounds__(256) void k_hist(const int* __restrict__ dst,
                                              int* __restrict__ cnt) {
  int e = blockIdx.x * 256 + threadIdx.x;
  if (e < E) atomicAdd(&cnt[dst[e]], 1);
}

__global__ __launch_bounds__(256) void k_scan(const int* __restrict__ cnt,
                                              int* __restrict__ row_ptr,
                                              int* __restrict__ cursor) {
  __shared__ int part[257];
  int t = threadIdx.x;
  const int CH = (N + 255) / 256;
  int lo = t * CH, hi = min(lo + CH, N);
  int s = 0;
  for (int i = lo; i < hi; ++i) s += cnt[i];
  part[t + 1] = s;
  __syncthreads();
  if (t == 0) {
    part[0] = 0;
    for (int i = 1; i <= 256; ++i) part[i] += part[i - 1];
  }
  __syncthreads();
  int run = part[t];
  for (int i = lo; i < hi; ++i) {
    row_ptr[i] = run;
    cursor[i]  = run;
    run += cnt[i];
  }
  if (t == 255) row_ptr[N] = part[256];
}

__global__ __launch_bounds__(256) void k_fill(const int* __restrict__ src,
                                              const int* __restrict__ dst,
                                              const int* __restrict__ etype,
                                              int* __restrict__ cursor,
                                              unsigned int* __restrict__ es) {
  int e = blockIdx.x * 256 + threadIdx.x;
  if (e < E) {
    int p = atomicAdd(&cursor[dst[e]], 1);
    es[p] = (unsigned int)src[e] | ((unsigned int)etype[e] << 16);  // src < 65536
  }
}

// ---- fused layer: CSR gather + boundary + linear + LN + relu + shortcut ----
// 512 threads = 8 waves, 8 nodes/wave, 625 blocks (all co-resident).
// No barriers in the node loop: rows[wid] is per-wave.
__global__ __launch_bounds__(512, 4) void k_layer(
    const float2* __restrict__ xo, float2* __restrict__ xn,
    const float2* __restrict__ rel2,             // [R*64] float2, this layer
    const int* __restrict__ row_ptr, const unsigned int* __restrict__ es,
    const float2* __restrict__ q2, const int* __restrict__ h_index,
    const float* __restrict__ lin_w, const float* __restrict__ lin_b,
    const float* __restrict__ ln_g, const float* __restrict__ ln_b,
    int layer, int first) {
  __shared__ float w[2 * D][D];        // 32 KB fp32, [k][out]
  __shared__ float bias_s[D], g_s[D], b_s[D];
  __shared__ float2 rows[8][2 * D];    // per-wave concat row, both batches
  int tid = threadIdx.x;
  const float* lw = lin_w + (size_t)layer * 2 * D * D;
  for (int i = tid; i < 2 * D * D; i += 512) (&w[0][0])[i] = lw[i];
  if (tid < D) {
    bias_s[tid] = lin_b[layer * D + tid];
    g_s[tid]    = ln_g[layer * D + tid];
    b_s[tid]    = ln_b[layer * D + tid];
  }
  int h0 = h_index[0], h1 = h_index[1];
  __syncthreads();                     // only barrier: weight staging
  int wid = tid >> 6, lane = tid & 63;
  int base = (blockIdx.x * 8 + wid) * 8;
  for (int ni = 0; ni < 8; ++ni) {
    int n = base + ni;
    float a0 = 0.f, a1 = 0.f;
    int rs = row_ptr[n], re = row_ptr[n + 1];
    if (first) {
      // layer 0: x nonzero only at h0 (.x) and h1 (.y)
      for (int j = rs; j < re; ++j) {
        unsigned int pk = es[j];
        int s  = (int)(pk & 0xffffu);
        int et = (int)(pk >> 16);
        if (s == h0) { float2 xv = xo[(size_t)s * D + lane];
                       float2 rv = rel2[et * D + lane];
                       a0 = fmaf(xv.x, rv.x, a0); }
        if (s == h1) { float2 xv = xo[(size_t)s * D + lane];
                       float2 rv = rel2[et * D + lane];
                       a1 = fmaf(xv.y, rv.y, a1); }
      }
    } else {
      int j = rs;
      for (; j + 2 <= re; j += 2) {    // unroll x2: 4 independent loads in flight
        unsigned int p0 = es[j], p1 = es[j + 1];
        int s0 = (int)(p0 & 0xffffu), e0 = (int)(p0 >> 16);
        int s1 = (int)(p1 & 0xffffu), e1 = (int)(p1 >> 16);
        float2 xa = xo[(size_t)s0 * D + lane];
        float2 ra = rel2[e0 * D + lane];
        float2 xb = xo[(size_t)s1 * D + lane];
        float2 rb = rel2[e1 * D + lane];
        a0 = fmaf(xa.x, ra.x, a0); a1 = fmaf(xa.y, ra.y, a1);
        a0 = fmaf(xb.x, rb.x, a0); a1 = fmaf(xb.y, rb.y, a1);
      }
      if (j < re) {
        unsigned int pk = es[j];
        int s  = (int)(pk & 0xffffu);
        int et = (int)(pk >> 16);
        float2 xv = xo[(size_t)s * D + lane];
        float2 rv = rel2[et * D + lane];
        a0 = fmaf(xv.x, rv.x, a0); a1 = fmaf(xv.y, rv.y, a1);
      }
    }
    if (n == h0) a0 += q2[lane].x;     // + boundary
    if (n == h1) a1 += q2[lane].y;
    float2 xv = xo[(size_t)n * D + lane];
    rows[wid][lane] = xv;
    rows[wid][D + lane] = make_float2(a0, a1);
    // same-wave LDS RAW: compiler orders via lgkmcnt, no barrier needed
    float o0 = bias_s[lane], o1 = o0;
    #pragma unroll 8
    for (int k = 0; k < 2 * D; ++k) {
      float2 r = rows[wid][k];         // wave-uniform broadcast
      float wk = w[k][lane];           // conflict-free (2-way alias is free)
      o0 = fmaf(r.x, wk, o0);
      o1 = fmaf(r.y, wk, o1);
    }
    // LayerNorm across 64 outputs (one per lane), both batches
    float s10 = o0, s20 = o0 * o0, s11 = o1, s21 = o1 * o1;
    #pragma unroll
    for (int m = 32; m > 0; m >>= 1) {
      s10 += __shfl_xor(s10, m); s20 += __shfl_xor(s20, m);
      s11 += __shfl_xor(s11, m); s21 += __shfl_xor(s21, m);
    }
    float mu0 = s10 * (1.f / D), var0 = s20 * (1.f / D) - mu0 * mu0;
    float mu1 = s11 * (1.f / D), var1 = s21 * (1.f / D) - mu1 * mu1;
    float r0 = fmaxf((o0 - mu0) * rsqrtf(var0 + EPS) * g_s[lane] + b_s[lane], 0.f) + xv.x;
    float r1 = fmaxf((o1 - mu1) * rsqrtf(var1 + EPS) * g_s[lane] + b_s[lane], 0.f) + xv.y;
    xn[(size_t)n * D + lane] = make_float2(r0, r1);
  }
}

// ---- final MLP: relu(concat(x, query) @ mlp_w + mlp_b) -> fp32 out ----
// 512 threads = 8 waves, 8 nodes/wave, 625 blocks; barrier-free node loop.
__global__ __launch_bounds__(512, 4) void k_mlp(
    const float2* __restrict__ x2, const float2* __restrict__ q2,
    const float* __restrict__ mlp_w,            // [2D][2D] row-major fp32
    const float* __restrict__ mlp_b,
    float2* __restrict__ out) {
  __shared__ unsigned int wp[2 * D][D];   // packed bf16 col-pairs, 32 KB
  __shared__ float2 rows[8][2 * D];
  int tid = threadIdx.x;
  for (int i = tid; i < 2 * D * D; i += 512) {
    float lo = mlp_w[2 * i];
    float hi = mlp_w[2 * i + 1];
    unsigned int ulo = (__float_as_uint(lo) + 0x8000u) >> 16;
    unsigned int uhi = (__float_as_uint(hi) + 0x8000u) & 0xffff0000u;
    (&wp[0][0])[i] = (ulo & 0xffffu) | uhi;
  }
  int wid = tid >> 6, lane = tid & 63;
  rows[wid][D + lane] = q2[lane];        // node-invariant half, per-wave region
  __syncthreads();                       // weight staging
  float b0 = mlp_b[2 * lane], b1 = mlp_b[2 * lane + 1];
  int base = (blockIdx.x * 8 + wid) * 8;
  for (int ni = 0; ni < 8; ++ni) {
    int n = base + ni;
    rows[wid][lane] = x2[(size_t)n * D + lane];
    float a00 = b0, a01 = b1, a10 = b0, a11 = b1;
    #pragma unroll 8
    for (int k = 0; k < 2 * D; ++k) {
      unsigned int pw = wp[k][lane];
      float wlo = __uint_as_float(pw << 16);
      float whi = __uint_as_float(pw & 0xffff0000u);
      float2 r = rows[wid][k];
      a00 = fmaf(r.x, wlo, a00); a01 = fmaf(r.x, whi, a01);
      a10 = fmaf(r.y, wlo, a10); a11 = fmaf(r.y, whi, a11);
    }
    float2 o0, o1;
    o0.x = fmaxf(a00, 0.f); o0.y = fmaxf(a01, 0.f);
    o1.x = fmaxf(a10, 0.f); o1.y = fmaxf(a11, 0.f);
    out[(size_t)n * D + lane] = o0;              // batch 0: elems n*128+2lane(+1)
    out[((size_t)N + n) * D + lane] = o1;        // batch 1
  }
}

}  // namespace

extern "C" void kernel_launch(void* const* d_in, const int* in_sizes, int n_in,
                              void* d_out, int out_size, void* d_ws, size_t ws_size,
                              hipStream_t stream) {
  const float* rel_reps = (const float*)d_in[0];
  const int* h_index    = (const int*)d_in[1];
  const int* r_index    = (const int*)d_in[2];
  const int* edge_index = (const int*)d_in[3];
  const int* edge_type  = (const int*)d_in[4];
  const float* proj_w1  = (const float*)d_in[5];
  const float* proj_b1  = (const float*)d_in[6];
  const float* proj_w2  = (const float*)d_in[7];
  const float* proj_b2  = (const float*)d_in[8];
  const float* lin_w    = (const float*)d_in[9];
  const float* lin_b    = (const float*)d_in[10];
  const float* ln_g     = (const float*)d_in[11];
  const float* ln_b     = (const float*)d_in[12];
  const float* mlp_w    = (const float*)d_in[13];
  const float* mlp_b    = (const float*)d_in[14];

  // workspace (floats): x0 | x1 | rel_all | query | cnt | row_ptr | cursor | es
  float* x0      = (float*)d_ws;                       // N*D float2
  float* x1      = x0 + (size_t)2 * N * D;
  float* rel_all = x1 + (size_t)2 * N * D;             // L*R*D float2
  float* query   = rel_all + (size_t)2 * L * R * D;    // D float2
  int*   cnt     = (int*)(query + 2 * D);
  int*   row_ptr = cnt + N;
  int*   cursor  = row_ptr + (N + 1);
  unsigned int* es = (unsigned int*)(cursor + N);

  const int* srcp = edge_index;
  const int* dstp = edge_index + E;

  hipMemsetAsync(x0, 0, (size_t)2 * N * D * sizeof(float), stream);
  hipMemsetAsync(cnt, 0, N * sizeof(int), stream);
  k_init<<<1, 128, 0, stream>>>(rel_reps, h_index, r_index, x0, query);
  k_rel<<<L * B * R, 64, 0, stream>>>(rel_reps, proj_w1, proj_b1, proj_w2, proj_b2, rel_all);
  k_hist<<<(E + 255) / 256, 256, 0, stream>>>(dstp, cnt);
  k_scan<<<1, 256, 0, stream>>>(cnt, row_ptr, cursor);
  k_fill<<<(E + 255) / 256, 256, 0, stream>>>(srcp, dstp, edge_type, cursor, es);

  float* xo = x0;
  float* xn = x1;
  for (int l = 0; l < L; ++l) {
    k_layer<<<N / 64, 512, 0, stream>>>((const float2*)xo, (float2*)xn,
                                        (const float2*)(rel_all + (size_t)2 * l * R * D),
                                        row_ptr, es, (const float2*)query, h_index,
                                        lin_w, lin_b, ln_g, ln_b, l, (l == 0) ? 1 : 0);
    float* t = xo; xo = xn; xn = t;
  }
  k_mlp<<<N / 64, 512, 0, stream>>>((const float2*)xo, (const float2*)query,
                                    mlp_w, mlp_b, (float2*)d_out);
}